// Round 1
// baseline (268.228 us; speedup 1.0000x reference)
//
#include <hip/hip_runtime.h>

typedef short bf16x8 __attribute__((ext_vector_type(8)));
typedef float f32x4  __attribute__((ext_vector_type(4)));

__device__ __forceinline__ unsigned short f2bf(float f) {
    unsigned int u = __float_as_uint(f);
    u += 0x7FFFu + ((u >> 16) & 1u);
    return (unsigned short)(u >> 16);
}

// ---------- fp32 -> bf16 elementwise (vectorized, grid-stride) ----------
__global__ void cvt_f32_bf16(const float* __restrict__ in,
                             unsigned short* __restrict__ out, int n4) {
    int stride = gridDim.x * blockDim.x;
    for (int i = blockIdx.x * blockDim.x + threadIdx.x; i < n4; i += stride) {
        float4 v = ((const float4*)in)[i];
        ushort4 r;
        r.x = f2bf(v.x); r.y = f2bf(v.y); r.z = f2bf(v.z); r.w = f2bf(v.w);
        ((ushort4*)out)[i] = r;
    }
}

// ---------- W2 [H][O] f32 -> W2T [O][H] bf16 (LDS tile transpose) ----------
__global__ void transpose_cvt(const float* __restrict__ in,
                              unsigned short* __restrict__ out, int H, int O) {
    __shared__ float tile[32][33];
    int o0 = blockIdx.x * 32, h0 = blockIdx.y * 32;
    int tx = threadIdx.x, ty = threadIdx.y;
    #pragma unroll
    for (int r = 0; r < 32; r += 8)
        tile[ty + r][tx] = in[(size_t)(h0 + ty + r) * O + o0 + tx];
    __syncthreads();
    #pragma unroll
    for (int r = 0; r < 32; r += 8) {
        int o = ty + r;
        out[(size_t)(o0 + o) * H + h0 + tx] = f2bf(tile[tx][o]);
    }
}

// ---------- BT GEMM: C[M,N] = A[M,K] * B[N,K]^T, bf16 in, fp32 acc ----------
// EPI=0: C = bf16 h, epilogue bias+exact GELU. EPI=1: C = fp32, no epilogue.
// 128x128 tile, BK=32, 256 threads (4 waves, 2x2), 16x16x32 MFMA, dbuf LDS.
template <int EPI>
__global__ __launch_bounds__(256) void gemm_bt(
    const unsigned short* __restrict__ A,
    const unsigned short* __restrict__ B,
    const float* __restrict__ bias,
    void* __restrict__ Cp,
    int N, int K) {
    __shared__ __align__(16) char lds[32768];
    const int t = threadIdx.x;
    const int w = t >> 6;
    const int l = t & 63;
    const int ntiles = N >> 7;
    const int mt = blockIdx.x / ntiles;
    const int nt = blockIdx.x % ntiles;
    const int m0 = mt << 7, n0 = nt << 7;
    const int wr = w >> 1, wc = w & 1;

    const int rowS0 = t >> 2;   // staging: row within 64-row half-tile
    const int cS    = t & 3;    // staging: 16B slot within 64B row

    f32x4 acc[4][4];
    {
        f32x4 z = {0.f, 0.f, 0.f, 0.f};
        #pragma unroll
        for (int i = 0; i < 4; ++i)
            #pragma unroll
            for (int j = 0; j < 4; ++j) acc[i][j] = z;
    }

    // Stage one 128x32 A-tile + 128x32 B-tile into LDS buffer b.
    // LDS dest is linear (global_load_lds requirement); the XOR slot swizzle
    // is applied on the global source and again on the read side.
    auto stage = [&](int b, int kt) {
        const int kb = kt << 5;
        #pragma unroll
        for (int i = 0; i < 2; ++i) {
            const int row  = (i << 6) + rowS0;
            const int csrc = cS ^ ((row >> 1) & 3);
            const unsigned short* ga = A + (size_t)(m0 + row) * K + kb + (csrc << 3);
            const unsigned short* gb = B + (size_t)(n0 + row) * K + kb + (csrc << 3);
            char* la = &lds[b * 16384 + i * 4096 + (w << 10)];
            char* lb = la + 8192;
            __builtin_amdgcn_global_load_lds((const __attribute__((address_space(1))) void*)ga,
                                             (__attribute__((address_space(3))) void*)la, 16, 0, 0);
            __builtin_amdgcn_global_load_lds((const __attribute__((address_space(1))) void*)gb,
                                             (__attribute__((address_space(3))) void*)lb, 16, 0, 0);
        }
    };

    // Per-lane LDS read offsets (invariant over K-loop)
    int aoff[4], boff[4];
    const int cR = l >> 4;
    #pragma unroll
    for (int mi = 0; mi < 4; ++mi) {
        int row = wr * 64 + mi * 16 + (l & 15);
        aoff[mi] = row * 64 + ((cR ^ ((row >> 1) & 3)) << 4);
    }
    #pragma unroll
    for (int ni = 0; ni < 4; ++ni) {
        int row = wc * 64 + ni * 16 + (l & 15);
        boff[ni] = 8192 + row * 64 + ((cR ^ ((row >> 1) & 3)) << 4);
    }

    const int NT = K >> 5;
    stage(0, 0);
    for (int kt = 0; kt < NT; ++kt) {
        __syncthreads();                    // stage(kt) landed (vmcnt drain at barrier)
        if (kt + 1 < NT) stage((kt + 1) & 1, kt + 1);
        const char* buf = &lds[(kt & 1) * 16384];
        bf16x8 af[4], bfv[4];
        #pragma unroll
        for (int mi = 0; mi < 4; ++mi) af[mi] = *(const bf16x8*)(buf + aoff[mi]);
        #pragma unroll
        for (int ni = 0; ni < 4; ++ni) bfv[ni] = *(const bf16x8*)(buf + boff[ni]);
        #pragma unroll
        for (int mi = 0; mi < 4; ++mi)
            #pragma unroll
            for (int ni = 0; ni < 4; ++ni)
                acc[mi][ni] = __builtin_amdgcn_mfma_f32_16x16x32_bf16(
                    af[mi], bfv[ni], acc[mi][ni], 0, 0, 0);
    }

    // Epilogue. C/D frag layout (m89-verified): col = lane&15, row = (lane>>4)*4 + j
    if constexpr (EPI == 0) {
        unsigned short* Cb = (unsigned short*)Cp;
        #pragma unroll
        for (int ni = 0; ni < 4; ++ni) {
            int col = n0 + wc * 64 + ni * 16 + (l & 15);
            float bv = bias[col];
            #pragma unroll
            for (int mi = 0; mi < 4; ++mi) {
                int rbase = m0 + wr * 64 + mi * 16 + ((l >> 4) << 2);
                f32x4 v4 = acc[mi][ni];
                #pragma unroll
                for (int j = 0; j < 4; ++j) {
                    float v = v4[j] + bv;
                    v = 0.5f * v * (1.0f + erff(v * 0.70710678118654752f));
                    Cb[(size_t)(rbase + j) * N + col] = f2bf(v);
                }
            }
        }
    } else {
        float* Cf = (float*)Cp;
        #pragma unroll
        for (int ni = 0; ni < 4; ++ni) {
            int col = n0 + wc * 64 + ni * 16 + (l & 15);
            #pragma unroll
            for (int mi = 0; mi < 4; ++mi) {
                int rbase = m0 + wr * 64 + mi * 16 + ((l >> 4) << 2);
                f32x4 v4 = acc[mi][ni];
                #pragma unroll
                for (int j = 0; j < 4; ++j)
                    Cf[(size_t)(rbase + j) * N + col] = v4[j];
            }
        }
    }
}

extern "C" void kernel_launch(void* const* d_in, const int* in_sizes, int n_in,
                              void* d_out, int out_size, void* d_ws, size_t ws_size,
                              hipStream_t stream) {
    const float* x  = (const float*)d_in[0];   // [T, 768]
    const float* w1 = (const float*)d_in[1];   // [3072, 768]
    const float* b1 = (const float*)d_in[2];   // [3072]
    const float* w2 = (const float*)d_in[3];   // [3072, 768]
    float* out = (float*)d_out;                // [T, 768] fp32

    const int T = 16384, DIN = 768, DH = 3072, DOUT = 768;

    unsigned short* xb  = (unsigned short*)d_ws;            // T*DIN bf16
    unsigned short* w1b = xb  + (size_t)T * DIN;            // DH*DIN bf16 (already [N][K])
    unsigned short* w2t = w1b + (size_t)DH * DIN;           // DOUT*DH bf16 ([N][K])
    unsigned short* h   = w2t + (size_t)DOUT * DH;          // CH*DH bf16

    size_t fixed = ((size_t)T * DIN + (size_t)DH * DIN + (size_t)DOUT * DH) * 2;
    int CH = T;
    while (CH > 128 && fixed + (size_t)CH * DH * 2 > ws_size) CH >>= 1;

    cvt_f32_bf16<<<2048, 256, 0, stream>>>(x, xb, T * DIN / 4);
    cvt_f32_bf16<<<1024, 256, 0, stream>>>(w1, w1b, DH * DIN / 4);
    transpose_cvt<<<dim3(DOUT / 32, DH / 32), dim3(32, 8), 0, stream>>>(w2, w2t, DH, DOUT);

    for (int c0 = 0; c0 < T; c0 += CH) {
        // h = GELU(x_chunk * W1^T + b)      M=CH, N=DH, K=DIN
        gemm_bt<0><<<(CH / 128) * (DH / 128), 256, 0, stream>>>(
            xb + (size_t)c0 * DIN, w1b, b1, h, DH, DIN);
        // out_chunk = h * W2T^T             M=CH, N=DOUT, K=DH
        gemm_bt<1><<<(CH / 128) * (DOUT / 128), 256, 0, stream>>>(
            h, w2t, b1, out + (size_t)c0 * DOUT, DOUT, DH);
    }
}

// Round 3
// 193.749 us; speedup vs baseline: 1.3844x; 1.3844x over previous
//
#include <hip/hip_runtime.h>

typedef short bf16x8 __attribute__((ext_vector_type(8)));
typedef float f32x4  __attribute__((ext_vector_type(4)));

__device__ __forceinline__ unsigned short f2bf(float f) {
    unsigned int u = __float_as_uint(f);
    u += 0x7FFFu + ((u >> 16) & 1u);
    return (unsigned short)(u >> 16);
}

// tanh-form GELU: x * sigmoid(2*0.79788456*(x + 0.044715 x^3)). |err| <~5e-4 abs.
__device__ __forceinline__ float gelu_f(float x) {
    float x2 = x * x;
    float u = x * (-1.5957691216f - 0.0713548162f * x2);
    float e = __expf(u);
    return x * __builtin_amdgcn_rcpf(1.0f + e);
}

// ---------- fp32 -> bf16 elementwise ----------
__global__ void cvt_f32_bf16(const float* __restrict__ in,
                             unsigned short* __restrict__ out, int n4) {
    int stride = gridDim.x * blockDim.x;
    for (int i = blockIdx.x * blockDim.x + threadIdx.x; i < n4; i += stride) {
        float4 v = ((const float4*)in)[i];
        ushort4 r;
        r.x = f2bf(v.x); r.y = f2bf(v.y); r.z = f2bf(v.z); r.w = f2bf(v.w);
        ((ushort4*)out)[i] = r;
    }
}

// ---------- W2 [H][O] f32 -> W2T [O][H] bf16 ----------
__global__ void transpose_cvt(const float* __restrict__ in,
                              unsigned short* __restrict__ out, int H, int O) {
    __shared__ float tile[32][33];
    int o0 = blockIdx.x * 32, h0 = blockIdx.y * 32;
    int tx = threadIdx.x, ty = threadIdx.y;
    #pragma unroll
    for (int r = 0; r < 32; r += 8)
        tile[ty + r][tx] = in[(size_t)(h0 + ty + r) * O + o0 + tx];
    __syncthreads();
    #pragma unroll
    for (int r = 0; r < 32; r += 8) {
        int o = ty + r;
        out[(size_t)(o0 + o) * H + h0 + tx] = f2bf(tile[tx][o]);
    }
}

// ---------- BT GEMM: C[M,N] = A[M,K]*B[N,K]^T, 256xBN tile, BK=64 ----------
// 512 threads = 8 waves (2M x 4N), per-wave 128 x BN/4, 16x16x32 MFMA.
// Counted-vmcnt pipeline (T4): stage(t+2) issued at end of iter t, vmcnt(L)
// (never 0) + raw s_barrier at iter top. Each stage sits alone between
// memory-clobber asm statements so vmcnt counting is exact; the prologue's
// two stages are separated by an explicit sched/memory barrier (R1 race fix).
// XOR slot-swizzle on 128B LDS rows: phys_slot = logical_slot ^ (row&7);
// inverse applied on global source (global_load_lds dest must stay linear),
// forward applied on ds_read address.
template <int EPI, int K, int N, int BN>
__global__ __launch_bounds__(512, 2) void gemm_bt(
    const unsigned short* __restrict__ A,
    const unsigned short* __restrict__ B,
    const float* __restrict__ bias,
    void* __restrict__ Cp) {
    constexpr int NREP = BN / 64;            // B-frag repeats per wave (4 or 3)
    constexpr int BHALF = 32768;             // A half size (256 rows x 128B)
    constexpr int LBUF = BHALF + BN * 128;   // one double-buffer slot
    __shared__ __align__(16) char lds[2 * LBUF];
    const int t = threadIdx.x;
    const int w = t >> 6, l = t & 63;
    constexpr int ntiles = N / BN;

    int bid = blockIdx.x;
    int nwg = gridDim.x;
    int wgid = ((nwg & 7) == 0) ? ((bid & 7) * (nwg >> 3) + (bid >> 3)) : bid;
    const int mt = wgid / ntiles, nt = wgid % ntiles;
    const int m0 = mt << 8, n0 = nt * BN;
    const int wr = w >> 2, wc = w & 3;

    // staging invariants: thread t covers row rA (per 64-row block), phys slot t&7
    const int rA = t >> 3;
    const int sl = (t & 7) ^ (rA & 7);       // logical k-slot landing in phys slot t&7

    auto stage = [&](int kt, char* dst) {
        const int kc = kt * 64 + sl * 8;
        #pragma unroll
        for (int i = 0; i < 4; ++i) {
            const unsigned short* ga = A + (size_t)(m0 + i * 64 + rA) * K + kc;
            char* la = dst + i * 8192 + (w << 10);
            __builtin_amdgcn_global_load_lds((const __attribute__((address_space(1))) void*)ga,
                                             (__attribute__((address_space(3))) void*)la, 16, 0, 0);
        }
        #pragma unroll
        for (int i = 0; i < NREP; ++i) {
            const unsigned short* gb = B + (size_t)(n0 + i * 64 + rA) * K + kc;
            char* lb = dst + BHALF + i * 8192 + (w << 10);
            __builtin_amdgcn_global_load_lds((const __attribute__((address_space(1))) void*)gb,
                                             (__attribute__((address_space(3))) void*)lb, 16, 0, 0);
        }
    };

    // ds_read base offsets (forward swizzle); row&7 == l&7 for every fragment row.
    const int swz = ((l >> 4) ^ (l & 7)) << 4;
    const int aoff0 = (wr * 128 + (l & 15)) * 128 + swz;
    const int aoffX = aoff0 ^ 64;            // ks=1: logical slot += 4  (k += 32)
    const int boff0 = BHALF + (wc * (BN / 4) + (l & 15)) * 128 + swz;
    const int boffX = boff0 ^ 64;

    f32x4 acc[8][NREP];
    {
        f32x4 z = {0.f, 0.f, 0.f, 0.f};
        #pragma unroll
        for (int i = 0; i < 8; ++i)
            #pragma unroll
            for (int j = 0; j < NREP; ++j) acc[i][j] = z;
    }

    constexpr int NT = K >> 6;
    stage(0, lds);
    __builtin_amdgcn_sched_barrier(0);
    asm volatile("" ::: "memory");           // R1 race fix: keep stage(0) older than stage(1)
    stage(1, lds + LBUF);

    for (int kt = 0; kt < NT; ++kt) {
        // stage(kt) are the oldest loads; leave the newest stage (4+NREP) in flight
        if constexpr (NREP == 4)
            asm volatile("s_waitcnt vmcnt(8)\n\ts_barrier" ::: "memory");
        else
            asm volatile("s_waitcnt vmcnt(7)\n\ts_barrier" ::: "memory");
        __builtin_amdgcn_sched_barrier(0);
        const char* base = lds + (kt & 1) * LBUF;
        bf16x8 av[4][2], bv[NREP][2];
        #pragma unroll
        for (int ni = 0; ni < NREP; ++ni) {
            bv[ni][0] = *(const bf16x8*)(base + boff0 + ni * 2048);
            bv[ni][1] = *(const bf16x8*)(base + boffX + ni * 2048);
        }
        #pragma unroll
        for (int mi = 0; mi < 4; ++mi) {
            av[mi][0] = *(const bf16x8*)(base + aoff0 + mi * 2048);
            av[mi][1] = *(const bf16x8*)(base + aoffX + mi * 2048);
        }
        #pragma unroll
        for (int ks = 0; ks < 2; ++ks)
            #pragma unroll
            for (int mi = 0; mi < 4; ++mi)
                #pragma unroll
                for (int ni = 0; ni < NREP; ++ni)
                    acc[mi][ni] = __builtin_amdgcn_mfma_f32_16x16x32_bf16(
                        av[mi][ks], bv[ni][ks], acc[mi][ni], 0, 0, 0);
        #pragma unroll
        for (int mi = 0; mi < 4; ++mi) {
            av[mi][0] = *(const bf16x8*)(base + aoff0 + (4 + mi) * 2048);
            av[mi][1] = *(const bf16x8*)(base + aoffX + (4 + mi) * 2048);
        }
        #pragma unroll
        for (int ks = 0; ks < 2; ++ks)
            #pragma unroll
            for (int mi = 0; mi < 4; ++mi)
                #pragma unroll
                for (int ni = 0; ni < NREP; ++ni)
                    acc[4 + mi][ni] = __builtin_amdgcn_mfma_f32_16x16x32_bf16(
                        av[mi][ks], bv[ni][ks], acc[4 + mi][ni], 0, 0, 0);
        // all waves done reading buf[kt&1] before anyone restages it
        __builtin_amdgcn_sched_barrier(0);
        asm volatile("s_waitcnt lgkmcnt(0)\n\ts_barrier" ::: "memory");
        __builtin_amdgcn_sched_barrier(0);
        if (kt + 2 < NT) stage(kt + 2, lds + (kt & 1) * LBUF);
    }

    // Epilogue. C/D frag: col = lane&15, row = (lane>>4)*4 + j  (m89-verified)
    if constexpr (EPI == 0) {
        unsigned short* Cb = (unsigned short*)Cp;
        #pragma unroll
        for (int ni = 0; ni < NREP; ++ni) {
            int col = n0 + wc * (BN / 4) + ni * 16 + (l & 15);
            float bvs = bias[col];
            #pragma unroll
            for (int mi = 0; mi < 8; ++mi) {
                int rbase = m0 + wr * 128 + mi * 16 + ((l >> 4) << 2);
                #pragma unroll
                for (int j = 0; j < 4; ++j) {
                    float v = acc[mi][ni][j] + bvs;
                    Cb[(size_t)(rbase + j) * N + col] = f2bf(gelu_f(v));
                }
            }
        }
    } else {
        float* Cf = (float*)Cp;
        #pragma unroll
        for (int ni = 0; ni < NREP; ++ni) {
            int col = n0 + wc * (BN / 4) + ni * 16 + (l & 15);
            #pragma unroll
            for (int mi = 0; mi < 8; ++mi) {
                int rbase = m0 + wr * 128 + mi * 16 + ((l >> 4) << 2);
                #pragma unroll
                for (int j = 0; j < 4; ++j)
                    Cf[(size_t)(rbase + j) * N + col] = acc[mi][ni][j];
            }
        }
    }
}

extern "C" void kernel_launch(void* const* d_in, const int* in_sizes, int n_in,
                              void* d_out, int out_size, void* d_ws, size_t ws_size,
                              hipStream_t stream) {
    const float* x  = (const float*)d_in[0];   // [T, 768]
    const float* w1 = (const float*)d_in[1];   // [3072, 768]
    const float* b1 = (const float*)d_in[2];   // [3072]
    const float* w2 = (const float*)d_in[3];   // [3072, 768]
    float* out = (float*)d_out;                // [T, 768] fp32

    const int T = 16384, DIN = 768, DH = 3072, DOUT = 768;

    unsigned short* xb  = (unsigned short*)d_ws;            // T*DIN bf16
    unsigned short* w1b = xb  + (size_t)T * DIN;            // DH*DIN bf16 ([N][K])
    unsigned short* w2t = w1b + (size_t)DH * DIN;           // DOUT*DH bf16 ([N][K])
    unsigned short* h   = w2t + (size_t)DOUT * DH;          // CH*DH bf16

    size_t fixed = ((size_t)T * DIN + (size_t)DH * DIN + (size_t)DOUT * DH) * 2;
    int CH = T;
    while (CH > 256 && fixed + (size_t)CH * DH * 2 > ws_size) CH >>= 1;

    cvt_f32_bf16<<<2048, 256, 0, stream>>>(x, xb, T * DIN / 4);
    cvt_f32_bf16<<<1024, 256, 0, stream>>>(w1, w1b, DH * DIN / 4);
    transpose_cvt<<<dim3(DOUT / 32, DH / 32), dim3(32, 8), 0, stream>>>(w2, w2t, DH, DOUT);

    for (int c0 = 0; c0 < T; c0 += CH) {
        // h = GELU(x_chunk * W1^T + b)      M=CH, N=DH=3072, K=DIN=768, BN=256
        gemm_bt<0, 768, 3072, 256><<<(CH / 256) * (DH / 256), 512, 0, stream>>>(
            xb + (size_t)c0 * DIN, w1b, b1, h);
        // out_chunk = h * W2T^T             M=CH, N=DOUT=768, K=DH=3072, BN=192
        gemm_bt<1, 3072, 768, 192><<<(CH / 256) * (DOUT / 192), 512, 0, stream>>>(
            h, w2t, b1, out + (size_t)c0 * DOUT);
    }
}